// Round 8
// baseline (404.031 us; speedup 1.0000x reference)
//
#include <hip/hip_runtime.h>
#include <math.h>

#define B 4
#define C 64
#define L 4096
#define OUTC 64
#define SCALE 10.0f
#define THRESH 1e-3f

// Staged-exp geometry: NS of 32 column-tiles staged in LDS as f16.
// EROW = NS*128 + 4 pad = 1924 ushorts; rows 4 apart differ by 3848
// dwords mod 32 = 8 banks, so the 4 quads' simultaneous ds_write_b16
// land on disjoint bank-groups {0,8,16,24}; within a quad 16 lanes span
// 8 banks at 2 lanes/bank (free, m136).
#define NS 15
#define SCOLS (NS * 128)                            // 1920 staged cols
#define EROW (SCOLS + 4)                            // 1924
#define SMEM_E_BYTES (16 * EROW * 2)                // 61568
#define SMEM_PT_OFF  SMEM_E_BYTES                   // Pt[2][16][132] f32
#define SMEM_PT_BYTES (2 * 16 * 132 * 4)            // 16896
#define SMEM_WSUM_OFF (SMEM_PT_OFF + SMEM_PT_BYTES) // 512 B: wsum[16][8]
#define SMEM_RINV_OFF (SMEM_WSUM_OFF + 512)         // 64 B: rinv[16]
#define SMEM_BYTES (SMEM_RINV_OFF + 64)             // 79040 -> 2 blocks/CU

typedef float v4f __attribute__((ext_vector_type(4)));
typedef short bf16x8 __attribute__((ext_vector_type(8)));
typedef unsigned short us8 __attribute__((ext_vector_type(8)));
typedef unsigned short us4 __attribute__((ext_vector_type(4)));

__device__ __forceinline__ unsigned short f2bf(float x) {
    unsigned int u = __float_as_uint(x);
    u += 0x7fffu + ((u >> 16) & 1u);          // round-to-nearest-even
    return (unsigned short)(u >> 16);
}
__device__ __forceinline__ float bf2f(unsigned short h) {
    return __uint_as_float(((unsigned int)h) << 16);
}
__device__ __forceinline__ v4f mfma16(bf16x8 a, bf16x8 b, v4f c) {
    return __builtin_amdgcn_mfma_f32_16x16x32_bf16(a, b, c, 0, 0, 0);
}

// ---------------------------------------------------------------------------
// FRAGMENT-TILED operand layout (ushort units):
//   T(b,tile,chunk,lane,j) = ((b*256 + tile)*2 + chunk)*512 + lane*8 + j
// tile = col/16, chunk = c/32, lane = ((c&31)>>3)*16 + (col&15), j = c&7.
// Fragment load = base + lane*16B -> one contiguous 1 KB wave transaction.
//
// R7 CHANGE — PARTIAL LDS REPLAY + PT-TRANSPOSE STORES (proven pieces only):
// Ledger-pinned constraints: (a) 16 waves/CU — every 8-waves/CU or spilling
// variant lost 13-50us (R1/R2/R3/R5); (b) output stores must be 1 KB
// instruction-contiguous — R6's 4x64B fragment-layout NT stores cost ~20us
// on partial-line HBM writes; (c) f16 LDS exp-staging is numerically free
// (R5/R6 absmax bit-identical). This round: stage NS=15/32 tiles' exp in
// 61.6 KB LDS, recompute the other 17 through R0's Pt-transpose store path
// (16.9 KB). 79.0 KB total keeps 2 blocks/CU. Pass-2 compute drops ~47%;
// staged cols become a pure LDS->HBM stream with zero barriers.
// XCD remap (batch b -> XCDs {2b,2b+1}) + NT output stores kept.
// ---------------------------------------------------------------------------

// ---------------------------------------------------------------------------
// Projection: p = l2norm(W2 @ leaky(W1 @ x)) per column, emitted as bf16
// hi/lo planes directly in the fragment-tiled layout above.
// 512 blocks x 256 threads; block->(which,b,ltile) decode is XCD-pinned.
// ---------------------------------------------------------------------------
__global__ void __launch_bounds__(256) proj_kernel(
    const float* __restrict__ q_in, const float* __restrict__ k_in,
    const float* __restrict__ W1, const float* __restrict__ W2,
    unsigned short* __restrict__ Qh, unsigned short* __restrict__ Ql,
    unsigned short* __restrict__ Kh, unsigned short* __restrict__ Kl)
{
    int bid   = blockIdx.x;        // 0..511
    int xcd   = bid & 7;
    int b     = xcd >> 1;
    int which = (bid >> 3) & 1;    // 0 = query, 1 = key
    int lt    = ((bid >> 4) << 1) | (xcd & 1);   // 0..63
    int l0    = lt << 6;
    int t     = threadIdx.x;
    int g     = t >> 6;            // 0..3  (owns channels [g*16, g*16+16))
    int l     = t & 63;

    const float* __restrict__ src =
        (which ? k_in : q_in) + (size_t)b * C * L + l0 + l;
    unsigned short* __restrict__ dh = which ? Kh : Qh;
    unsigned short* __restrict__ dl = which ? Kl : Ql;

    __shared__ float Ht[128][65];   // [h][l], pad 65 -> conflict-free
    __shared__ float red[4][64];

    float xr[C];
    #pragma unroll
    for (int c = 0; c < C; ++c)
        xr[c] = src[(size_t)c * L];

    // Stage 1: H[o][l] for o in [g*32, g*32+32)
    #pragma unroll 1
    for (int oo = 0; oo < 32; oo += 4) {
        #pragma unroll
        for (int u = 0; u < 4; ++u) {
            int o = g * 32 + oo + u;
            float h0 = 0.f, h1 = 0.f, h2 = 0.f, h3 = 0.f;
            #pragma unroll
            for (int c = 0; c < C; c += 4) {
                h0 = fmaf(W1[o * C + c + 0], xr[c + 0], h0);
                h1 = fmaf(W1[o * C + c + 1], xr[c + 1], h1);
                h2 = fmaf(W1[o * C + c + 2], xr[c + 2], h2);
                h3 = fmaf(W1[o * C + c + 3], xr[c + 3], h3);
            }
            float h = (h0 + h1) + (h2 + h3);
            Ht[o][l] = (h >= 0.0f) ? h : 0.01f * h;   // LeakyReLU(0.01)
        }
    }
    __syncthreads();

    // Stage 2: Y[o][l] for o in [g*16, g*16+16)
    float y[16];
    #pragma unroll
    for (int u = 0; u < 16; ++u) y[u] = 0.f;

    #pragma unroll 1
    for (int hh = 0; hh < 2 * C; hh += 16) {
        float hr[16];
        #pragma unroll
        for (int r = 0; r < 16; ++r)
            hr[r] = Ht[hh + r][l];
        #pragma unroll
        for (int u = 0; u < 16; ++u) {
            int o = g * 16 + u;
            #pragma unroll
            for (int h = 0; h < 16; ++h)
                y[u] = fmaf(W2[o * (2 * C) + hh + h], hr[h], y[u]);
        }
    }

    // l2norm over all 64 output channels (cross-group via LDS)
    float ss = 0.f;
    #pragma unroll
    for (int u = 0; u < 16; ++u) ss = fmaf(y[u], y[u], ss);
    red[g][l] = ss;
    __syncthreads();
    float tot = red[0][l] + red[1][l] + red[2][l] + red[3][l];
    float inv = 1.0f / fmaxf(sqrtf(tot), 1e-12f);

    // Emit bf16 hi/lo split in fragment-tiled layout.
    unsigned short hs[16], ls[16];
    #pragma unroll
    for (int u = 0; u < 16; ++u) {
        float val = y[u] * inv;
        hs[u] = f2bf(val);
        ls[u] = f2bf(val - bf2f(hs[u]));
    }
    {
        int col   = l0 + l;
        int tile  = col >> 4;
        int lnn   = col & 15;
        int chunk = g >> 1;
        int quad0 = (g & 1) * 2;
        size_t base0 = (((size_t)b * 256 + tile) * 2 + chunk) * 512
                     + (size_t)(quad0 * 16 + lnn) * 8;
        size_t base1 = base0 + 128;   // quad0+1 -> lane+16 -> +128 ushorts
        *(us8*)(dh + base0) = *(us8*)&hs[0];
        *(us8*)(dh + base1) = *(us8*)&hs[8];
        *(us8*)(dl + base0) = *(us8*)&ls[0];
        *(us8*)(dl + base1) = *(us8*)&ls[8];
    }
}

// Load the 4 K-plane fragments of absolute column-tile TILE.
#define LOADK(TILE) do {                                                 \
    size_t _kb = ((ktb + (size_t)(TILE)) * 2) * 512 + (size_t)lane * 8;  \
    kh0 = *(const bf16x8*)(Kh + _kb);                                    \
    kl0 = *(const bf16x8*)(Kl + _kb);                                    \
    kh1 = *(const bf16x8*)(Kh + _kb + 512);                              \
    kl1 = *(const bf16x8*)(Kl + _kb + 512);                              \
} while (0)

#define DOMFMA() do {                                                    \
    acc = (v4f){0.f, 0.f, 0.f, 0.f};                                     \
    acc = mfma16(aQ[0][0], kh0, acc);                                    \
    acc = mfma16(aQ[0][1], kh0, acc);                                    \
    acc = mfma16(aQ[0][0], kl0, acc);                                    \
    acc = mfma16(aQ[1][0], kh1, acc);                                    \
    acc = mfma16(aQ[1][1], kh1, acc);                                    \
    acc = mfma16(aQ[1][0], kl1, acc);                                    \
} while (0)

// ---------------------------------------------------------------------------
// Scores kernel: partial LDS replay with Pt-transpose recompute stores.
// 1024 blocks (XCD-pinned decode) x 512 threads (8 waves); 16 q-rows per
// block; 79.0 KB dynamic LDS -> 2 blocks/CU (16 waves).
// Phase 1: exp(S-10) once for all 32 tiles; tiles 0..NS-1 staged as f16
//          in e_t, f32 row sums.
// Phase 2b: recompute tiles NS..31 via the R0-proven Pt transpose ->
//           1 KB instruction-contiguous NT stores.
// Phase 2a: stream staged cols from e_t (no barriers, pure write stream).
// S = Qh*Kh + Qh*Kl + Ql*Kh (lo*lo dropped). |S|<=10 -> fixed shift 10.
// ---------------------------------------------------------------------------
__global__ void __launch_bounds__(512) scores_kernel(
    const unsigned short* __restrict__ Qh, const unsigned short* __restrict__ Ql,
    const unsigned short* __restrict__ Kh, const unsigned short* __restrict__ Kl,
    float* __restrict__ out)
{
    extern __shared__ unsigned char smem[];
    unsigned short* __restrict__ e_t  = (unsigned short*)smem;            // [16][EROW]
    float*          __restrict__ Pt   = (float*)(smem + SMEM_PT_OFF);     // [2][16][132]
    float*          __restrict__ wsum = (float*)(smem + SMEM_WSUM_OFF);   // [16][8]
    float*          __restrict__ rinv = (float*)(smem + SMEM_RINV_OFF);   // [16]

    int bid  = blockIdx.x;          // 0..1023
    // XCD-locality decode: batch b = (bid&7)>>1.
    int xcd  = bid & 7;
    int b    = xcd >> 1;
    int r0   = (((bid >> 3) << 1) | (xcd & 1)) << 4;   // 16 rows, 0..4080
    int t    = threadIdx.x;
    int wave = t >> 6;
    int lane = t & 63;
    int quad = lane >> 4;
    int ln   = lane & 15;
    int wave16ln = wave * 16 + ln;
    int rowbase  = quad * 4;

    // A fragments (fragment-tiled): aQ[c0][hi/lo], one 16-row tile
    bf16x8 aQ[2][2];
    {
        size_t rowtile = (size_t)b * 256 + (r0 >> 4);
        #pragma unroll
        for (int c0 = 0; c0 < 2; ++c0) {
            size_t base = (rowtile * 2 + c0) * 512 + (size_t)lane * 8;
            aQ[c0][0] = *(const bf16x8*)(Qh + base);
            aQ[c0][1] = *(const bf16x8*)(Ql + base);
        }
    }

    const size_t ktb = (size_t)b * 256;
    bf16x8 kh0, kl0, kh1, kl1;
    v4f acc;
    v4f ps = (v4f){0.f, 0.f, 0.f, 0.f};

    // ---------------- phase 1: compute exp(S-10) once ---------------------
    // STRIDED column assignment: iteration i covers tile i*8 + wave, i.e.
    // global cols i*128 + wave*16 + [0,16) -> e_t col == global col.
    #pragma unroll 2
    for (int i = 0; i < NS; ++i) {              // staged tiles
        LOADK(i * 8 + wave);
        DOMFMA();
        #pragma unroll
        for (int r = 0; r < 4; ++r) {
            float ev = __expf(fmaf(SCALE, acc[r], -SCALE));
            ps[r] += ev;
            e_t[(rowbase + r) * EROW + i * 128 + wave16ln] =
                __builtin_bit_cast(unsigned short, (_Float16)ev);
        }
    }
    #pragma unroll 2
    for (int i = NS; i < 32; ++i) {             // sum-only tiles
        LOADK(i * 8 + wave);
        DOMFMA();
        #pragma unroll
        for (int r = 0; r < 4; ++r)
            ps[r] += __expf(fmaf(SCALE, acc[r], -SCALE));
    }

    // reduce over the 16 ln-lanes (cols) per row, then across waves via LDS
    #pragma unroll
    for (int r = 0; r < 4; ++r) {
        float s = ps[r];
        s += __shfl_xor(s, 1);
        s += __shfl_xor(s, 2);
        s += __shfl_xor(s, 4);
        s += __shfl_xor(s, 8);
        if (ln == 0) wsum[(rowbase + r) * 8 + wave] = s;
    }
    __syncthreads();
    if (t < 16) {
        float s = 0.f;
        #pragma unroll
        for (int w = 0; w < 8; ++w) s += wsum[t * 8 + w];
        rinv[t] = 1.0f / s;
    }
    __syncthreads();

    float rv[4];
    #pragma unroll
    for (int r = 0; r < 4; ++r)
        rv[r] = rinv[rowbase + r];

    float* __restrict__ outb = out + ((size_t)b * L + r0) * L;
    int srow = t >> 5;            // 0..15 (store row)
    int scol = (t & 31) * 4;      // 0..124 (16 B-aligned col)

    // ---------------- phase 2b: recompute tiles NS..31 via Pt transpose ---
    // R0-proven path: MFMA -> Pt[buf] -> sync -> 1 KB-contiguous NT store.
    // buf reuse at T+2 is separated by the sync at T+1 (safe, 1 sync/tile).
    #pragma unroll 1
    for (int T = NS; T < 32; ++T) {
        int buf = T & 1;
        LOADK(T * 8 + wave);
        DOMFMA();
        #pragma unroll
        for (int r = 0; r < 4; ++r) {
            float w = __expf(fmaf(SCALE, acc[r], -SCALE)) * rv[r];
            w = (w > THRESH) ? w : 0.f;
            // C/D layout: col = ln, row = quad*4 + r (m89/m91)
            Pt[(buf * 16 + rowbase + r) * 132 + wave16ln] = w;
        }
        __syncthreads();

        // line-complete cooperative store: 512 lanes x 16 B contiguous,
        // non-temporal so the store stream doesn't evict resident K planes.
        v4f o = *(const v4f*)&Pt[(buf * 16 + srow) * 132 + scol];
        __builtin_nontemporal_store(
            o, (v4f*)(outb + (size_t)srow * L + T * 128 + scol));
    }

    // ---------------- phase 2a: stream staged cols from LDS ---------------
    // Thread t owns row t>>5, cols (t&31)*4 + 128*it, it in [0, NS).
    {
        float ri = rinv[srow];
        const unsigned short* __restrict__ erow = e_t + (size_t)srow * EROW;
        float* __restrict__ orow = outb + (size_t)srow * L;

        #pragma unroll 2
        for (int it = 0; it < NS; ++it) {
            int col = it * 128 + scol;
            us4 hv = *(const us4*)(erow + col);
            v4f o;
            #pragma unroll
            for (int j = 0; j < 4; ++j) {
                float w = (float)__builtin_bit_cast(_Float16,
                                                    (unsigned short)hv[j]) * ri;
                o[j] = (w > THRESH) ? w : 0.f;
            }
            __builtin_nontemporal_store(o, (v4f*)(orow + col));
        }
    }
}

// ---------------------------------------------------------------------------
extern "C" void kernel_launch(void* const* d_in, const int* in_sizes, int n_in,
                              void* d_out, int out_size, void* d_ws, size_t ws_size,
                              hipStream_t stream) {
    const float* query = (const float*)d_in[0];
    const float* key   = (const float*)d_in[1];
    const float* W1    = (const float*)d_in[2];
    const float* W2    = (const float*)d_in[3];
    float* out = (float*)d_out;

    // ws layout (ushorts): Qh | Ql | Kh | Kl, each B*L*OUTC = 1048576 elems
    unsigned short* Qh = (unsigned short*)d_ws;
    unsigned short* Ql = Qh + (size_t)B * L * OUTC;
    unsigned short* Kh = Ql + (size_t)B * L * OUTC;
    unsigned short* Kl = Kh + (size_t)B * L * OUTC;

    hipLaunchKernelGGL(proj_kernel, dim3(512), dim3(256), 0, stream,
                       query, key, W1, W2, Qh, Ql, Kh, Kl);
    hipLaunchKernelGGL(scores_kernel, dim3(1024), dim3(512), SMEM_BYTES, stream,
                       Qh, Ql, Kh, Kl, out);
}

// Round 9
// 363.135 us; speedup vs baseline: 1.1126x; 1.1126x over previous
//
#include <hip/hip_runtime.h>
#include <math.h>

#define B 4
#define C 64
#define L 4096
#define OUTC 64
#define SCALE 10.0f
#define THRESH 1e-3f

typedef float v4f __attribute__((ext_vector_type(4)));
typedef short bf16x8 __attribute__((ext_vector_type(8)));
typedef unsigned short us8 __attribute__((ext_vector_type(8)));

__device__ __forceinline__ unsigned short f2bf(float x) {
    unsigned int u = __float_as_uint(x);
    u += 0x7fffu + ((u >> 16) & 1u);          // round-to-nearest-even
    return (unsigned short)(u >> 16);
}
__device__ __forceinline__ float bf2f(unsigned short h) {
    return __uint_as_float(((unsigned int)h) << 16);
}
__device__ __forceinline__ v4f mfma16(bf16x8 a, bf16x8 b, v4f c) {
    return __builtin_amdgcn_mfma_f32_16x16x32_bf16(a, b, c, 0, 0, 0);
}

// ---------------------------------------------------------------------------
// FRAGMENT-TILED operand layout (ushort units):
//   T(b,tile,chunk,lane,j) = ((b*256 + tile)*2 + chunk)*512 + lane*8 + j
// tile = col/16, chunk = c/32, lane = ((c&31)>>3)*16 + (col&15), j = c&7.
// Fragment load = base + lane*16B -> one contiguous 1 KB wave transaction.
//
// R8 — TERMINAL REVERT TO THE BEST-MEASURED KERNEL (R0, 361.6 us).
// Nine-measurement ledger: 512 blocks x 32 rows x 2-pass recompute with
// Pt-transpose 1 KB stores + XCD remap + NT stores is the plateau; every
// departure lost 13-50 us:
//   - VGPR replay: R1 (1 blk/CU, 382.5), R2/R3 (launch_bounds spill,
//     378.9/414.9 — VGPR_Count=64 + 142 MB scratch traffic).
//   - LDS replay (1024 blk x 16 rows): doubles chip-level K traffic to
//     >=1.07 GB in phase 1 ALONE (per-block accounting hid this);
//     R5/R6/R7 = 377/385/404.
//   - Fragment-layout 4x64B NT stores (R6): partial-line HBM writes.
//   - Pipelining pass1/pass2 (R4): neutral (364.2) — the barrier drain
//     was never the exposed cost.
// Timed total decomposes: ~213 us harness poison fills at ~80% HBM peak
// (rooflined, untouchable) + ~14 us proj + ~135 us scores (plateau).
// ---------------------------------------------------------------------------

// ---------------------------------------------------------------------------
// Projection: p = l2norm(W2 @ leaky(W1 @ x)) per column, emitted as bf16
// hi/lo planes directly in the fragment-tiled layout above.
// 512 blocks x 256 threads; block->(which,b,ltile) decode is XCD-pinned.
// ---------------------------------------------------------------------------
__global__ void __launch_bounds__(256) proj_kernel(
    const float* __restrict__ q_in, const float* __restrict__ k_in,
    const float* __restrict__ W1, const float* __restrict__ W2,
    unsigned short* __restrict__ Qh, unsigned short* __restrict__ Ql,
    unsigned short* __restrict__ Kh, unsigned short* __restrict__ Kl)
{
    int bid   = blockIdx.x;        // 0..511
    // XCD-locality decode: xcd = bid & 7; batch b = xcd>>1 (2 XCDs/batch),
    // column-tile parity = xcd & 1. Bijective over (which, b, lt).
    int xcd   = bid & 7;
    int b     = xcd >> 1;
    int which = (bid >> 3) & 1;    // 0 = query, 1 = key
    int lt    = ((bid >> 4) << 1) | (xcd & 1);   // 0..63
    int l0    = lt << 6;
    int t     = threadIdx.x;
    int g     = t >> 6;            // 0..3  (owns channels [g*16, g*16+16))
    int l     = t & 63;

    const float* __restrict__ src =
        (which ? k_in : q_in) + (size_t)b * C * L + l0 + l;
    unsigned short* __restrict__ dh = which ? Kh : Qh;
    unsigned short* __restrict__ dl = which ? Kl : Ql;

    __shared__ float Ht[128][65];   // [h][l], pad 65 -> conflict-free
    __shared__ float red[4][64];

    float xr[C];
    #pragma unroll
    for (int c = 0; c < C; ++c)
        xr[c] = src[(size_t)c * L];

    // Stage 1: H[o][l] for o in [g*32, g*32+32)
    #pragma unroll 1
    for (int oo = 0; oo < 32; oo += 4) {
        #pragma unroll
        for (int u = 0; u < 4; ++u) {
            int o = g * 32 + oo + u;
            float h0 = 0.f, h1 = 0.f, h2 = 0.f, h3 = 0.f;
            #pragma unroll
            for (int c = 0; c < C; c += 4) {
                h0 = fmaf(W1[o * C + c + 0], xr[c + 0], h0);
                h1 = fmaf(W1[o * C + c + 1], xr[c + 1], h1);
                h2 = fmaf(W1[o * C + c + 2], xr[c + 2], h2);
                h3 = fmaf(W1[o * C + c + 3], xr[c + 3], h3);
            }
            float h = (h0 + h1) + (h2 + h3);
            Ht[o][l] = (h >= 0.0f) ? h : 0.01f * h;   // LeakyReLU(0.01)
        }
    }
    __syncthreads();

    // Stage 2: Y[o][l] for o in [g*16, g*16+16)
    float y[16];
    #pragma unroll
    for (int u = 0; u < 16; ++u) y[u] = 0.f;

    #pragma unroll 1
    for (int hh = 0; hh < 2 * C; hh += 16) {
        float hr[16];
        #pragma unroll
        for (int r = 0; r < 16; ++r)
            hr[r] = Ht[hh + r][l];
        #pragma unroll
        for (int u = 0; u < 16; ++u) {
            int o = g * 16 + u;
            #pragma unroll
            for (int h = 0; h < 16; ++h)
                y[u] = fmaf(W2[o * (2 * C) + hh + h], hr[h], y[u]);
        }
    }

    // l2norm over all 64 output channels (cross-group via LDS)
    float ss = 0.f;
    #pragma unroll
    for (int u = 0; u < 16; ++u) ss = fmaf(y[u], y[u], ss);
    red[g][l] = ss;
    __syncthreads();
    float tot = red[0][l] + red[1][l] + red[2][l] + red[3][l];
    float inv = 1.0f / fmaxf(sqrtf(tot), 1e-12f);

    // Emit bf16 hi/lo split in fragment-tiled layout.
    // Channels c = g*16+u: chunk = g>>1; u<8 -> quad = (g&1)*2, j=u;
    // u>=8 -> quad = (g&1)*2+1, j=u-8.
    unsigned short hs[16], ls[16];
    #pragma unroll
    for (int u = 0; u < 16; ++u) {
        float val = y[u] * inv;
        hs[u] = f2bf(val);
        ls[u] = f2bf(val - bf2f(hs[u]));
    }
    {
        int col   = l0 + l;
        int tile  = col >> 4;
        int lnn   = col & 15;
        int chunk = g >> 1;
        int quad0 = (g & 1) * 2;
        size_t base0 = (((size_t)b * 256 + tile) * 2 + chunk) * 512
                     + (size_t)(quad0 * 16 + lnn) * 8;
        size_t base1 = base0 + 128;   // quad0+1 -> lane+16 -> +128 ushorts
        *(us8*)(dh + base0) = *(us8*)&hs[0];
        *(us8*)(dh + base1) = *(us8*)&hs[8];
        *(us8*)(dl + base0) = *(us8*)&ls[0];
        *(us8*)(dl + base1) = *(us8*)&ls[8];
    }
}

// ---------------------------------------------------------------------------
// Merged scores kernel: MFMA bf16x3, softmax(fixed shift 10), threshold.
// 512 blocks (XCD-pinned decode) x 512 threads (8 waves); 32 q-rows/block.
// S = Qh*Kh + Qh*Kl + Ql*Kh (lo*lo dropped, ~4e-5 logit error). |S|<=10 so
// the softmax shift is the constant 10 (exp(S-10) in [2e-9,1], no max pass).
// ALL operand loads are fragment-tiled: base + lane*16B, fully contiguous
// 1 KB per wave instruction. Pass-2 output stores are NON-TEMPORAL so the
// 268 MB store stream does not evict the L2-resident K planes.
// ---------------------------------------------------------------------------
__global__ void __launch_bounds__(512) scores_kernel(
    const unsigned short* __restrict__ Qh, const unsigned short* __restrict__ Ql,
    const unsigned short* __restrict__ Kh, const unsigned short* __restrict__ Kl,
    float* __restrict__ out)
{
    int bid  = blockIdx.x;          // 0..511
    // XCD-locality decode: batch b = (bid&7)>>1 -> all blocks on one XCD
    // share one batch's K/Q planes (~1.5 MB hot set < 4 MiB private L2).
    int xcd  = bid & 7;
    int b    = xcd >> 1;
    int r0   = (((bid >> 3) << 1) | (xcd & 1)) << 5;   // 32 rows, 0..4064
    int t    = threadIdx.x;
    int wave = t >> 6;
    int lane = t & 63;
    int quad = lane >> 4;
    int ln   = lane & 15;

    // A fragments (fragment-tiled): aQ[rt][c0][hi/lo]
    bf16x8 aQ[2][2][2];
    {
        #pragma unroll
        for (int rt = 0; rt < 2; ++rt) {
            size_t rowtile = (size_t)b * 256 + (r0 >> 4) + rt;
            #pragma unroll
            for (int c0 = 0; c0 < 2; ++c0) {
                size_t base = (rowtile * 2 + c0) * 512 + (size_t)lane * 8;
                aQ[rt][c0][0] = *(const bf16x8*)(Qh + base);
                aQ[rt][c0][1] = *(const bf16x8*)(Ql + base);
            }
        }
    }

    const size_t ktb = (size_t)b * 256;
    __shared__ float wsum[32][8];
    __shared__ float rinv[32];
    __shared__ float Pt[2][32][132];   // double-buffered transpose tile

    // ---------------- pass 1: row sums of exp(S - 10) ----------------
    v4f ps[2];
    ps[0] = (v4f){0.f, 0.f, 0.f, 0.f};
    ps[1] = (v4f){0.f, 0.f, 0.f, 0.f};

    #pragma unroll 1
    for (int ct = 0; ct < 32; ++ct) {
        size_t base = ((ktb + wave * 32 + ct) * 2) * 512 + (size_t)lane * 8;
        bf16x8 bh0 = *(const bf16x8*)(Kh + base);
        bf16x8 bl0 = *(const bf16x8*)(Kl + base);
        bf16x8 bh1 = *(const bf16x8*)(Kh + base + 512);
        bf16x8 bl1 = *(const bf16x8*)(Kl + base + 512);

        #pragma unroll
        for (int rt = 0; rt < 2; ++rt) {
            v4f acc = (v4f){0.f, 0.f, 0.f, 0.f};
            acc = mfma16(aQ[rt][0][0], bh0, acc);
            acc = mfma16(aQ[rt][0][1], bh0, acc);
            acc = mfma16(aQ[rt][0][0], bl0, acc);
            acc = mfma16(aQ[rt][1][0], bh1, acc);
            acc = mfma16(aQ[rt][1][1], bh1, acc);
            acc = mfma16(aQ[rt][1][0], bl1, acc);
            #pragma unroll
            for (int r = 0; r < 4; ++r)
                ps[rt][r] += __expf(fmaf(SCALE, acc[r], -SCALE));
        }
    }

    // reduce over the 16 ln-lanes (cols) per row, then across waves via LDS
    #pragma unroll
    for (int rt = 0; rt < 2; ++rt) {
        #pragma unroll
        for (int r = 0; r < 4; ++r) {
            float s = ps[rt][r];
            s += __shfl_xor(s, 1);
            s += __shfl_xor(s, 2);
            s += __shfl_xor(s, 4);
            s += __shfl_xor(s, 8);
            if (ln == 0) wsum[rt * 16 + quad * 4 + r][wave] = s;
        }
    }
    __syncthreads();
    if (t < 32) {
        float s = 0.f;
        #pragma unroll
        for (int w = 0; w < 8; ++w) s += wsum[t][w];
        rinv[t] = 1.0f / s;
    }
    __syncthreads();

    float rv[2][4];
    #pragma unroll
    for (int rt = 0; rt < 2; ++rt)
        #pragma unroll
        for (int r = 0; r < 4; ++r)
            rv[rt][r] = rinv[rt * 16 + quad * 4 + r];

    // ---------------- pass 2: recompute, normalize, threshold, store ------
    float* __restrict__ outb = out + ((size_t)b * L + r0) * L;
    int srow = t >> 5;            // 0..15 (store row within half-tile)
    int scol = (t & 31) * 4;      // 0..124 (16 B-aligned col)

    #pragma unroll 1
    for (int T = 0; T < 32; ++T) {
        int buf = T & 1;
        size_t base = ((ktb + T * 8 + wave) * 2) * 512 + (size_t)lane * 8;
        bf16x8 bh0 = *(const bf16x8*)(Kh + base);
        bf16x8 bl0 = *(const bf16x8*)(Kl + base);
        bf16x8 bh1 = *(const bf16x8*)(Kh + base + 512);
        bf16x8 bl1 = *(const bf16x8*)(Kl + base + 512);

        #pragma unroll
        for (int rt = 0; rt < 2; ++rt) {
            v4f acc = (v4f){0.f, 0.f, 0.f, 0.f};
            acc = mfma16(aQ[rt][0][0], bh0, acc);
            acc = mfma16(aQ[rt][0][1], bh0, acc);
            acc = mfma16(aQ[rt][0][0], bl0, acc);
            acc = mfma16(aQ[rt][1][0], bh1, acc);
            acc = mfma16(aQ[rt][1][1], bh1, acc);
            acc = mfma16(aQ[rt][1][0], bl1, acc);
            #pragma unroll
            for (int r = 0; r < 4; ++r) {
                float w = __expf(fmaf(SCALE, acc[r], -SCALE)) * rv[rt][r];
                w = (w > THRESH) ? w : 0.f;
                // C/D layout: col = ln, row = quad*4 + r (m89/m91)
                Pt[buf][rt * 16 + quad * 4 + r][wave * 16 + ln] = w;
            }
        }
        __syncthreads();

        // instruction-level line-complete cooperative store:
        // each instruction = 64 lanes x 16 B fully contiguous (1 KiB),
        // non-temporal so it does not evict the resident K planes.
        #pragma unroll
        for (int j = 0; j < 2; ++j) {
            int row = j * 16 + srow;
            v4f o = *(const v4f*)&Pt[buf][row][scol];
            __builtin_nontemporal_store(
                o, (v4f*)(outb + (size_t)row * L + T * 128 + scol));
        }
    }
}

// ---------------------------------------------------------------------------
extern "C" void kernel_launch(void* const* d_in, const int* in_sizes, int n_in,
                              void* d_out, int out_size, void* d_ws, size_t ws_size,
                              hipStream_t stream) {
    const float* query = (const float*)d_in[0];
    const float* key   = (const float*)d_in[1];
    const float* W1    = (const float*)d_in[2];
    const float* W2    = (const float*)d_in[3];
    float* out = (float*)d_out;

    // ws layout (ushorts): Qh | Ql | Kh | Kl, each B*L*OUTC = 1048576 elems
    unsigned short* Qh = (unsigned short*)d_ws;
    unsigned short* Ql = Qh + (size_t)B * L * OUTC;
    unsigned short* Kh = Ql + (size_t)B * L * OUTC;
    unsigned short* Kl = Kh + (size_t)B * L * OUTC;

    hipLaunchKernelGGL(proj_kernel, dim3(512), dim3(256), 0, stream,
                       query, key, W1, W2, Qh, Ql, Kh, Kl);
    hipLaunchKernelGGL(scores_kernel, dim3(512), dim3(512), 0, stream,
                       Qh, Ql, Kh, Kl, out);
}